// Round 3
// baseline (390.304 us; speedup 1.0000x reference)
//
#include <hip/hip_runtime.h>

#define Tn 64
#define Bn 16384
#define Vn 29
#define Hn 20

typedef float f4 __attribute__((ext_vector_type(4)));

static __device__ __forceinline__ f4 ld4u(const float* p) {
  f4 v; __builtin_memcpy(&v, p, 16); return v;
}
static __device__ __forceinline__ void st4u(float* p, f4 v) {
  __builtin_memcpy(p, &v, 16);
}

#define LOG2E 1.4426950408889634f
#define LN2   0.6931471805599453f

static __device__ __forceinline__ float frcp(float x) {
#if __has_builtin(__builtin_amdgcn_rcpf)
  return __builtin_amdgcn_rcpf(x);
#else
  return 1.0f / x;
#endif
}
static __device__ __forceinline__ float fexp2(float x) {
#if __has_builtin(__builtin_amdgcn_exp2f)
  return __builtin_amdgcn_exp2f(x);
#else
  return exp2f(x);
#endif
}
static __device__ __forceinline__ float flog2(float x) {
#if __has_builtin(__builtin_amdgcn_logf)
  return __builtin_amdgcn_logf(x);
#else
  return log2f(x);
#endif
}
static __device__ __forceinline__ float ftanh(float x) {
  float e = fexp2(x * (2.0f * LOG2E));
  return 1.0f - 2.0f * frcp(1.0f + e);
}

// lane swizzle (BitMode): src = ((lane & and) | or) ^ xor, within 32-lane halves
#define SWZ(v, imm) __int_as_float(__builtin_amdgcn_ds_swizzle(__float_as_int(v), (imm)))
#define PAT(ow) (((ow) << 5) | 0x18)   /* broadcast from lane `ow` of each 8-group */

// one term of the xi dot: c is a LITERAL -> PAT((c)>>2) is a constant expr
#define XI_STEP(xv, c) { \
  float xb_ = SWZ((xv)[(c) & 3], PAT((c) >> 2)); \
  a0 += wi0[(c)] * xb_; a1 += wi1[(c)] * xb_; a2 += wi2[(c)] * xb_; }

#define XI_ALL(xv) \
  XI_STEP(xv, 0)  XI_STEP(xv, 1)  XI_STEP(xv, 2)  XI_STEP(xv, 3)  \
  XI_STEP(xv, 4)  XI_STEP(xv, 5)  XI_STEP(xv, 6)  XI_STEP(xv, 7)  \
  XI_STEP(xv, 8)  XI_STEP(xv, 9)  XI_STEP(xv, 10) XI_STEP(xv, 11) \
  XI_STEP(xv, 12) XI_STEP(xv, 13) XI_STEP(xv, 14) XI_STEP(xv, 15) \
  XI_STEP(xv, 16) XI_STEP(xv, 17) XI_STEP(xv, 18) XI_STEP(xv, 19) \
  XI_STEP(xv, 20) XI_STEP(xv, 21) XI_STEP(xv, 22) XI_STEP(xv, 23) \
  XI_STEP(xv, 24) XI_STEP(xv, 25) XI_STEP(xv, 26) XI_STEP(xv, 27) \
  XI_STEP(xv, 28)

// lane j<7 holds x[row, 4j..4j+3]; lane 7 holds x[row,28] in .x
static __device__ __forceinline__ f4 ldx(const float* row, int j) {
  f4 v;
  if (j < 7) v = ld4u(row + 4 * j);
  else       v = f4{row[28], 0.0f, 0.0f, 0.0f};
  return v;
}

// ---------------------------------------------------------------------------
// Fully fused: per t, compute xi = x@Wi^T (+bias [+img at t=0]) via 8-lane
// x-broadcast, recurrence h = tanh(xi + h@Wh^T), logits, log-softmax.
// 8 lanes per batch element; all weights register-resident.
// ---------------------------------------------------------------------------
__global__ __launch_bounds__(256, 1) void k_fused(
    const float* __restrict__ x,   const float* __restrict__ img,
    const float* __restrict__ Wi,  const float* __restrict__ bi,
    const float* __restrict__ Wh,  const float* __restrict__ bh,
    const float* __restrict__ Who, const float* __restrict__ bho,
    float* __restrict__ out)
{
  const int gt = blockIdx.x * 256 + threadIdx.x;
  const int b = gt >> 3;
  const int j = gt & 7;

  int r0 = 3 * j;     r0 = r0 > 19 ? 19 : r0;
  int r1 = 3 * j + 1; r1 = r1 > 19 ? 19 : r1;
  int r2 = 3 * j + 2; r2 = r2 > 19 ? 19 : r2;

  // ---- Wi rows (29 floats, rows NOT 16B-aligned -> unaligned loads) ----
  float wi0[Vn], wi1[Vn], wi2[Vn];
#pragma unroll
  for (int q = 0; q < 7; ++q) {
    f4 a = ld4u(Wi + r0 * Vn + 4 * q);
    f4 c = ld4u(Wi + r1 * Vn + 4 * q);
    f4 d = ld4u(Wi + r2 * Vn + 4 * q);
    wi0[4*q]=a.x; wi0[4*q+1]=a.y; wi0[4*q+2]=a.z; wi0[4*q+3]=a.w;
    wi1[4*q]=c.x; wi1[4*q+1]=c.y; wi1[4*q+2]=c.z; wi1[4*q+3]=c.w;
    wi2[4*q]=d.x; wi2[4*q+1]=d.y; wi2[4*q+2]=d.z; wi2[4*q+3]=d.w;
  }
  wi0[28] = Wi[r0 * Vn + 28];
  wi1[28] = Wi[r1 * Vn + 28];
  wi2[28] = Wi[r2 * Vn + 28];

  // ---- Wh rows (20 floats, 80B rows -> 16B-aligned) ----
  float wh0[Hn], wh1[Hn], wh2[Hn];
#pragma unroll
  for (int q = 0; q < 5; ++q) {
    f4 a = *(const f4*)(Wh + r0 * Hn + 4 * q);
    f4 c = *(const f4*)(Wh + r1 * Hn + 4 * q);
    f4 d = *(const f4*)(Wh + r2 * Hn + 4 * q);
    wh0[4*q]=a.x; wh0[4*q+1]=a.y; wh0[4*q+2]=a.z; wh0[4*q+3]=a.w;
    wh1[4*q]=c.x; wh1[4*q+1]=c.y; wh1[4*q+2]=c.z; wh1[4*q+3]=c.w;
    wh2[4*q]=d.x; wh2[4*q+1]=d.y; wh2[4*q+2]=d.z; wh2[4*q+3]=d.w;
  }

  // ---- Who rows: lane j owns vocab rows 4j..4j+3 (clamped), bias-masked ----
  float wo[4][Hn], bo[4];
#pragma unroll
  for (int rr = 0; rr < 4; ++rr) {
    int v = 4 * j + rr; int vc = v > 28 ? 28 : v;
#pragma unroll
    for (int q = 0; q < 5; ++q) {
      f4 w = *(const f4*)(Who + vc * Hn + 4 * q);
      wo[rr][4*q]=w.x; wo[rr][4*q+1]=w.y; wo[rr][4*q+2]=w.z; wo[rr][4*q+3]=w.w;
    }
    bo[rr] = (v < Vn) ? bho[v] : -1e30f;
  }

  const float bs0 = bi[r0] + bh[r0];
  const float bs1 = bi[r1] + bh[r1];
  const float bs2 = bi[r2] + bh[r2];

  const size_t S = (size_t)Bn * Vn;           // floats per timestep of x
  const float* xrow = x + (size_t)b * Vn;

  // prologue: x(0) used now; x(1), x(2) prefetched
  f4 xv = ldx(xrow, j);
  f4 xA = ldx(xrow + S, j);
  f4 xB = ldx(xrow + 2 * S, j);
  const float* pf = xrow + 3 * S;

  // xi(0) = x(0)@Wi^T + (bi+bh) + img
  float a0 = 0.0f, a1 = 0.0f, a2 = 0.0f;
  XI_ALL(xv)
  a0 += bs0 + img[(size_t)b * Hn + r0];
  a1 += bs1 + img[(size_t)b * Hn + r1];
  a2 += bs2 + img[(size_t)b * Hn + r2];

  float hbc[Hn];
#pragma unroll
  for (int k = 0; k < Hn; ++k) hbc[k] = 0.0f;

  float* op = out + (size_t)b * Vn + 4 * j;
  const size_t ostep = (size_t)Bn * Vn;

#pragma unroll 1
  for (int t = 0; t < Tn; ++t) {
    // prefetch x(t+3) (clamped to last row; redundant re-reads are L1 hits)
    f4 xC = ldx(pf, j);
    if (t < 60) pf += S;

    // ---- h_t = tanh(xi_t + h_{t-1} @ Wh^T) ----
    float A0 = a0, A1 = a1, A2 = a2;
#pragma unroll
    for (int k = 0; k < Hn; ++k) {
      float hk = hbc[k];
      A0 += hk * wh0[k]; A1 += hk * wh1[k]; A2 += hk * wh2[k];
    }
    float h0 = ftanh(A0), h1 = ftanh(A1), h2 = ftanh(A2);

    // broadcast h_t across the 8-lane group: owner(k)=min(k/3,6)
    hbc[0]  = SWZ(h0, PAT(0)); hbc[1]  = SWZ(h1, PAT(0)); hbc[2]  = SWZ(h2, PAT(0));
    hbc[3]  = SWZ(h0, PAT(1)); hbc[4]  = SWZ(h1, PAT(1)); hbc[5]  = SWZ(h2, PAT(1));
    hbc[6]  = SWZ(h0, PAT(2)); hbc[7]  = SWZ(h1, PAT(2)); hbc[8]  = SWZ(h2, PAT(2));
    hbc[9]  = SWZ(h0, PAT(3)); hbc[10] = SWZ(h1, PAT(3)); hbc[11] = SWZ(h2, PAT(3));
    hbc[12] = SWZ(h0, PAT(4)); hbc[13] = SWZ(h1, PAT(4)); hbc[14] = SWZ(h2, PAT(4));
    hbc[15] = SWZ(h0, PAT(5)); hbc[16] = SWZ(h1, PAT(5)); hbc[17] = SWZ(h2, PAT(5));
    hbc[18] = SWZ(h0, PAT(6)); hbc[19] = SWZ(h1, PAT(6));

    // ---- logits (4 vocab rows/lane) ----
    float l0 = bo[0], l1 = bo[1], l2 = bo[2], l3 = bo[3];
#pragma unroll
    for (int k = 0; k < Hn; ++k) {
      float hk = hbc[k];
      l0 += hk * wo[0][k]; l1 += hk * wo[1][k];
      l2 += hk * wo[2][k]; l3 += hk * wo[3][k];
    }

    // ---- log-softmax over the 8-lane group ----
    float m = fmaxf(fmaxf(l0, l1), fmaxf(l2, l3));
    m = fmaxf(m, SWZ(m, 0x041F));
    m = fmaxf(m, SWZ(m, 0x081F));
    m = fmaxf(m, SWZ(m, 0x101F));
    float e0 = fexp2((l0 - m) * LOG2E), e1 = fexp2((l1 - m) * LOG2E);
    float e2 = fexp2((l2 - m) * LOG2E), e3 = fexp2((l3 - m) * LOG2E);
    float s = e0 + e1 + e2 + e3;
    s += SWZ(s, 0x041F);
    s += SWZ(s, 0x081F);
    s += SWZ(s, 0x101F);
    float ls = m + flog2(s) * LN2;

    f4 o = f4{l0 - ls, l1 - ls, l2 - ls, l3 - ls};
    if (j < 7) st4u(op, o);
    else       op[0] = l0 - ls;
    op += ostep;

    // ---- xi(t+1) = x(t+1)@Wi^T + (bi+bh), overlaps with everything above ----
    a0 = 0.0f; a1 = 0.0f; a2 = 0.0f;
    XI_ALL(xA)
    a0 += bs0; a1 += bs1; a2 += bs2;

    xA = xB; xB = xC;
  }
}

extern "C" void kernel_launch(void* const* d_in, const int* in_sizes, int n_in,
                              void* d_out, int out_size, void* d_ws, size_t ws_size,
                              hipStream_t stream)
{
  const float* x   = (const float*)d_in[0];
  const float* img = (const float*)d_in[1];
  const float* Wi  = (const float*)d_in[2];
  const float* bi  = (const float*)d_in[3];
  const float* Wh  = (const float*)d_in[4];
  const float* bh  = (const float*)d_in[5];
  const float* Who = (const float*)d_in[6];
  const float* bho = (const float*)d_in[7];
  float* out = (float*)d_out;

  // 8 lanes per batch element, one fused kernel, no workspace
  k_fused<<<(8 * Bn) / 256, 256, 0, stream>>>(x, img, Wi, bi, Wh, bh, Who, bho, out);
}

// Round 4
// 378.495 us; speedup vs baseline: 1.0312x; 1.0312x over previous
//
#include <hip/hip_runtime.h>

#define Tn 64
#define Bn 16384
#define Vn 29
#define Hn 20

typedef float f4 __attribute__((ext_vector_type(4)));

static __device__ __forceinline__ f4 ld4u(const float* p) {
  f4 v; __builtin_memcpy(&v, p, 16); return v;
}
static __device__ __forceinline__ void st4u(float* p, f4 v) {
  __builtin_memcpy(p, &v, 16);
}

#define LOG2E 1.4426950408889634f
#define LN2   0.6931471805599453f

static __device__ __forceinline__ float frcp(float x) {
#if __has_builtin(__builtin_amdgcn_rcpf)
  return __builtin_amdgcn_rcpf(x);
#else
  return 1.0f / x;
#endif
}
static __device__ __forceinline__ float fexp2(float x) {
#if __has_builtin(__builtin_amdgcn_exp2f)
  return __builtin_amdgcn_exp2f(x);
#else
  return exp2f(x);
#endif
}
static __device__ __forceinline__ float flog2(float x) {
#if __has_builtin(__builtin_amdgcn_logf)
  return __builtin_amdgcn_logf(x);
#else
  return log2f(x);
#endif
}
static __device__ __forceinline__ float ftanh(float x) {
  float e = fexp2(x * (2.0f * LOG2E));
  return 1.0f - 2.0f * frcp(1.0f + e);
}

// lane swizzle (BitMode): src = ((lane & and) | or) ^ xor, within 32-lane halves
#define SWZ(v, imm) __int_as_float(__builtin_amdgcn_ds_swizzle(__float_as_int(v), (imm)))
#define PAT(ow) (((ow) << 5) | 0x18)   /* broadcast from lane `ow` of each 8-group */

// DPP cross-lane (VALU-speed) for xor1/xor2 within quads
#if __has_builtin(__builtin_amdgcn_update_dpp)
#define DPPF(v, ctrl) __int_as_float(__builtin_amdgcn_update_dpp( \
    0, __float_as_int(v), (ctrl), 0xF, 0xF, true))
#define DPP_XOR1(v) DPPF(v, 0xB1)   /* quad_perm [1,0,3,2] */
#define DPP_XOR2(v) DPPF(v, 0x4E)   /* quad_perm [2,3,0,1] */
#else
#define DPP_XOR1(v) SWZ(v, 0x041F)
#define DPP_XOR2(v) SWZ(v, 0x081F)
#endif

// one term of the xi dot: c is a LITERAL -> PAT((c)>>2) is a constant expr
#define XI_STEP(xv, c) { \
  float xb_ = SWZ((xv)[(c) & 3], PAT((c) >> 2)); \
  a0 += wi0[(c)] * xb_; a1 += wi1[(c)] * xb_; a2 += wi2[(c)] * xb_; }

#define XI_ALL(xv) \
  XI_STEP(xv, 0)  XI_STEP(xv, 1)  XI_STEP(xv, 2)  XI_STEP(xv, 3)  \
  XI_STEP(xv, 4)  XI_STEP(xv, 5)  XI_STEP(xv, 6)  XI_STEP(xv, 7)  \
  XI_STEP(xv, 8)  XI_STEP(xv, 9)  XI_STEP(xv, 10) XI_STEP(xv, 11) \
  XI_STEP(xv, 12) XI_STEP(xv, 13) XI_STEP(xv, 14) XI_STEP(xv, 15) \
  XI_STEP(xv, 16) XI_STEP(xv, 17) XI_STEP(xv, 18) XI_STEP(xv, 19) \
  XI_STEP(xv, 20) XI_STEP(xv, 21) XI_STEP(xv, 22) XI_STEP(xv, 23) \
  XI_STEP(xv, 24) XI_STEP(xv, 25) XI_STEP(xv, 26) XI_STEP(xv, 27) \
  XI_STEP(xv, 28)

// lane j<7 holds x[row, 4j..4j+3]; lane 7 holds x[row,28] in .x
static __device__ __forceinline__ f4 ldx(const float* row, int j) {
  f4 v;
  if (j < 7) v = ld4u(row + 4 * j);
  else       v = f4{row[28], 0.0f, 0.0f, 0.0f};
  return v;
}

// ---------------------------------------------------------------------------
// Fully fused RNN step. 8 lanes per batch element, ALL weights register-
// resident (~290 floats/lane). amdgpu_waves_per_eu(1,1) forces a 1-wave/EU
// allocation so the unified 512-reg VGPR/AGPR file holds them with NO spill
// (round-3 post-mortem: default heuristic capped at 172 regs and spilled).
// ---------------------------------------------------------------------------
__global__ __attribute__((amdgpu_waves_per_eu(1, 1))) __launch_bounds__(256)
void k_fused(
    const float* __restrict__ x,   const float* __restrict__ img,
    const float* __restrict__ Wi,  const float* __restrict__ bi,
    const float* __restrict__ Wh,  const float* __restrict__ bh,
    const float* __restrict__ Who, const float* __restrict__ bho,
    float* __restrict__ out)
{
  const int gt = blockIdx.x * 256 + threadIdx.x;
  const int b = gt >> 3;
  const int j = gt & 7;

  int r0 = 3 * j;     r0 = r0 > 19 ? 19 : r0;
  int r1 = 3 * j + 1; r1 = r1 > 19 ? 19 : r1;
  int r2 = 3 * j + 2; r2 = r2 > 19 ? 19 : r2;

  // ---- Wi rows (29 floats each, unaligned rows) ----
  float wi0[Vn], wi1[Vn], wi2[Vn];
#pragma unroll
  for (int q = 0; q < 7; ++q) {
    f4 a = ld4u(Wi + r0 * Vn + 4 * q);
    f4 c = ld4u(Wi + r1 * Vn + 4 * q);
    f4 d = ld4u(Wi + r2 * Vn + 4 * q);
    wi0[4*q]=a.x; wi0[4*q+1]=a.y; wi0[4*q+2]=a.z; wi0[4*q+3]=a.w;
    wi1[4*q]=c.x; wi1[4*q+1]=c.y; wi1[4*q+2]=c.z; wi1[4*q+3]=c.w;
    wi2[4*q]=d.x; wi2[4*q+1]=d.y; wi2[4*q+2]=d.z; wi2[4*q+3]=d.w;
  }
  wi0[28] = Wi[r0 * Vn + 28];
  wi1[28] = Wi[r1 * Vn + 28];
  wi2[28] = Wi[r2 * Vn + 28];

  // ---- Wh rows (20 floats, 80B rows -> 16B-aligned) ----
  float wh0[Hn], wh1[Hn], wh2[Hn];
#pragma unroll
  for (int q = 0; q < 5; ++q) {
    f4 a = *(const f4*)(Wh + r0 * Hn + 4 * q);
    f4 c = *(const f4*)(Wh + r1 * Hn + 4 * q);
    f4 d = *(const f4*)(Wh + r2 * Hn + 4 * q);
    wh0[4*q]=a.x; wh0[4*q+1]=a.y; wh0[4*q+2]=a.z; wh0[4*q+3]=a.w;
    wh1[4*q]=c.x; wh1[4*q+1]=c.y; wh1[4*q+2]=c.z; wh1[4*q+3]=c.w;
    wh2[4*q]=d.x; wh2[4*q+1]=d.y; wh2[4*q+2]=d.z; wh2[4*q+3]=d.w;
  }

  // ---- Who rows: lane j owns vocab rows 4j..4j+3 (clamped), bias-masked ----
  float wo[4][Hn], bo[4];
#pragma unroll
  for (int rr = 0; rr < 4; ++rr) {
    int v = 4 * j + rr; int vc = v > 28 ? 28 : v;
#pragma unroll
    for (int q = 0; q < 5; ++q) {
      f4 w = *(const f4*)(Who + vc * Hn + 4 * q);
      wo[rr][4*q]=w.x; wo[rr][4*q+1]=w.y; wo[rr][4*q+2]=w.z; wo[rr][4*q+3]=w.w;
    }
    bo[rr] = (v < Vn) ? bho[v] : -1e30f;
  }

  const float bs0 = bi[r0] + bh[r0];
  const float bs1 = bi[r1] + bh[r1];
  const float bs2 = bi[r2] + bh[r2];

  const size_t S = (size_t)Bn * Vn;           // floats per timestep of x
  const float* xrow = x + (size_t)b * Vn;

  // prologue: x(0) used now; x(1), x(2) prefetched
  f4 xv = ldx(xrow, j);
  f4 xA = ldx(xrow + S, j);
  f4 xB = ldx(xrow + 2 * S, j);
  const float* pf = xrow + 3 * S;

  // xi(0) = x(0)@Wi^T + (bi+bh) + img
  float a0 = 0.0f, a1 = 0.0f, a2 = 0.0f;
  XI_ALL(xv)
  a0 += bs0 + img[(size_t)b * Hn + r0];
  a1 += bs1 + img[(size_t)b * Hn + r1];
  a2 += bs2 + img[(size_t)b * Hn + r2];

  float hbc[Hn];
#pragma unroll
  for (int k = 0; k < Hn; ++k) hbc[k] = 0.0f;

  float* op = out + (size_t)b * Vn + 4 * j;
  const size_t ostep = (size_t)Bn * Vn;

#pragma unroll 1
  for (int t = 0; t < Tn; ++t) {
    // prefetch x(t+3) (clamped to last row; redundant re-reads are L1 hits)
    f4 xC = ldx(pf, j);
    if (t < 60) pf += S;

    // ---- h_t = tanh(xi_t + h_{t-1} @ Wh^T) ----
    float A0 = a0, A1 = a1, A2 = a2;
#pragma unroll
    for (int k = 0; k < Hn; ++k) {
      float hk = hbc[k];
      A0 += hk * wh0[k]; A1 += hk * wh1[k]; A2 += hk * wh2[k];
    }
    float h0 = ftanh(A0), h1 = ftanh(A1), h2 = ftanh(A2);

    // broadcast h_t across the 8-lane group: owner(k)=min(k/3,6)
    hbc[0]  = SWZ(h0, PAT(0)); hbc[1]  = SWZ(h1, PAT(0)); hbc[2]  = SWZ(h2, PAT(0));
    hbc[3]  = SWZ(h0, PAT(1)); hbc[4]  = SWZ(h1, PAT(1)); hbc[5]  = SWZ(h2, PAT(1));
    hbc[6]  = SWZ(h0, PAT(2)); hbc[7]  = SWZ(h1, PAT(2)); hbc[8]  = SWZ(h2, PAT(2));
    hbc[9]  = SWZ(h0, PAT(3)); hbc[10] = SWZ(h1, PAT(3)); hbc[11] = SWZ(h2, PAT(3));
    hbc[12] = SWZ(h0, PAT(4)); hbc[13] = SWZ(h1, PAT(4)); hbc[14] = SWZ(h2, PAT(4));
    hbc[15] = SWZ(h0, PAT(5)); hbc[16] = SWZ(h1, PAT(5)); hbc[17] = SWZ(h2, PAT(5));
    hbc[18] = SWZ(h0, PAT(6)); hbc[19] = SWZ(h1, PAT(6));

    // ---- logits (4 vocab rows/lane) ----
    float l0 = bo[0], l1 = bo[1], l2 = bo[2], l3 = bo[3];
#pragma unroll
    for (int k = 0; k < Hn; ++k) {
      float hk = hbc[k];
      l0 += hk * wo[0][k]; l1 += hk * wo[1][k];
      l2 += hk * wo[2][k]; l3 += hk * wo[3][k];
    }

    // ---- log-softmax over the 8-lane group (DPP for xor1/xor2, swz xor4) ----
    float m = fmaxf(fmaxf(l0, l1), fmaxf(l2, l3));
    m = fmaxf(m, DPP_XOR1(m));
    m = fmaxf(m, DPP_XOR2(m));
    m = fmaxf(m, SWZ(m, 0x101F));
    float e0 = fexp2((l0 - m) * LOG2E), e1 = fexp2((l1 - m) * LOG2E);
    float e2 = fexp2((l2 - m) * LOG2E), e3 = fexp2((l3 - m) * LOG2E);
    float s = e0 + e1 + e2 + e3;
    s += DPP_XOR1(s);
    s += DPP_XOR2(s);
    s += SWZ(s, 0x101F);
    float ls = m + flog2(s) * LN2;

    f4 o = f4{l0 - ls, l1 - ls, l2 - ls, l3 - ls};
    if (j < 7) st4u(op, o);
    else       op[0] = l0 - ls;
    op += ostep;

    // ---- xi(t+1) = x(t+1)@Wi^T + (bi+bh), overlaps with everything above ----
    a0 = 0.0f; a1 = 0.0f; a2 = 0.0f;
    XI_ALL(xA)
    a0 += bs0; a1 += bs1; a2 += bs2;

    xA = xB; xB = xC;
  }
}

extern "C" void kernel_launch(void* const* d_in, const int* in_sizes, int n_in,
                              void* d_out, int out_size, void* d_ws, size_t ws_size,
                              hipStream_t stream)
{
  const float* x   = (const float*)d_in[0];
  const float* img = (const float*)d_in[1];
  const float* Wi  = (const float*)d_in[2];
  const float* bi  = (const float*)d_in[3];
  const float* Wh  = (const float*)d_in[4];
  const float* bh  = (const float*)d_in[5];
  const float* Who = (const float*)d_in[6];
  const float* bho = (const float*)d_in[7];
  float* out = (float*)d_out;

  // 8 lanes per batch element, one fused kernel, no workspace
  k_fused<<<(8 * Bn) / 256, 256, 0, stream>>>(x, img, Wi, bi, Wh, bh, Who, bho, out);
}